// Round 1
// baseline (444.178 us; speedup 1.0000x reference)
//
#include <hip/hip_runtime.h>
#include <hip/hip_bf16.h>
#include <stdint.h>

typedef __attribute__((ext_vector_type(8))) short bf16x8;
typedef __attribute__((ext_vector_type(4))) float f32x4;
typedef __attribute__((ext_vector_type(4))) unsigned short us4;

#define TILE_M 128
#define TILE_N 128
#define TILE_K 32

__device__ __forceinline__ unsigned short f2b(float f) {
  union { float f; unsigned u; } u;
  u.f = f;
  unsigned r = u.u + 0x7fffu + ((u.u >> 16) & 1u);
  return (unsigned short)(r >> 16);
}

__device__ __forceinline__ void gload_lds16(const void* g, void* lds) {
  __builtin_amdgcn_global_load_lds(
      (const __attribute__((address_space(1))) unsigned int*)(uintptr_t)g,
      (__attribute__((address_space(3))) unsigned int*)(uintptr_t)lds,
      16, 0, 0);
}

// Stage a 128x32 bf16 tile (8KB) into LDS. 256 threads, 16B per lane per issue.
// g points at (row0, k0) already-offset K-base; element (row0+row)*ld + col.
__device__ __forceinline__ void stage_tile(const unsigned short* __restrict__ g,
                                           long ld, long row0,
                                           unsigned short* lds, int tid) {
  int w = tid >> 6, lane = tid & 63;
#pragma unroll
  for (int j = 0; j < 2; ++j) {
    int o = ((w * 2 + j) << 10) + lane * 16;  // byte offset in 8KB tile
    int row = o >> 6;                          // 64 B per row (32 bf16)
    int col = (o & 63) >> 1;                   // element within row
    const unsigned short* gp = g + (row0 + row) * ld + col;
    gload_lds16(gp, (char*)lds + ((w * 2 + j) << 10));
  }
}

// ---------------- GEMM1: qkv = x @ W^T + b  (bf16 out) ----------------
__global__ __launch_bounds__(256, 2) void gemm1_qkv(
    const unsigned short* __restrict__ A,   // x bf16 [16384][1024]
    const unsigned short* __restrict__ Bm,  // W bf16 [3072][1024]
    const float* __restrict__ bias,         // [3072] f32
    unsigned short* __restrict__ C) {       // qkv bf16 [16384][3072]
  __shared__ unsigned short lsA[TILE_M * TILE_K];
  __shared__ unsigned short lsB[TILE_N * TILE_K];
  int tid = threadIdx.x;
  int lane = tid & 63, w = tid >> 6;
  int wr = w >> 1, wc = w & 1;
  long bm0 = (long)blockIdx.y * TILE_M;
  long bn0 = (long)blockIdx.x * TILE_N;
  f32x4 acc[4][4] = {};
  int r = lane & 15, g = lane >> 4;
  for (int kt = 0; kt < 1024 / TILE_K; ++kt) {
    long k0 = (long)kt * TILE_K;
    stage_tile(A + k0, 1024, bm0, lsA, tid);
    stage_tile(Bm + k0, 1024, bn0, lsB, tid);
    __syncthreads();
    bf16x8 aF[4], bF[4];
#pragma unroll
    for (int m = 0; m < 4; ++m)
      aF[m] = *(const bf16x8*)(lsA + (wr * 64 + m * 16 + r) * 32 + g * 8);
#pragma unroll
    for (int n = 0; n < 4; ++n)
      bF[n] = *(const bf16x8*)(lsB + (wc * 64 + n * 16 + r) * 32 + g * 8);
#pragma unroll
    for (int m = 0; m < 4; ++m)
#pragma unroll
      for (int n = 0; n < 4; ++n)
        acc[m][n] = __builtin_amdgcn_mfma_f32_16x16x32_bf16(aF[m], bF[n], acc[m][n], 0, 0, 0);
    __syncthreads();
  }
#pragma unroll
  for (int n = 0; n < 4; ++n) {
    long col = bn0 + wc * 64 + n * 16 + r;
    float bv = bias[col];
#pragma unroll
    for (int m = 0; m < 4; ++m)
#pragma unroll
      for (int j = 0; j < 4; ++j) {
        long row = bm0 + wr * 64 + m * 16 + g * 4 + j;
        C[row * 3072 + col] = f2b(acc[m][n][j] + bv);
      }
  }
}

// ------------- GEMM2: scores = tril(q @ k^T) * inv_scale (bf16) -------------
__global__ __launch_bounds__(256, 2) void gemm2_scores(
    const unsigned short* __restrict__ qkv,  // [16384][3072]
    unsigned short* __restrict__ scores,     // [8][2048][2048]
    float inv_scale) {
  int bj = blockIdx.x, bi = blockIdx.y, b = blockIdx.z;
  if (bj > bi) return;  // strictly-above-diagonal blocks are never read
  __shared__ unsigned short lsA[TILE_M * TILE_K];
  __shared__ unsigned short lsB[TILE_N * TILE_K];
  int tid = threadIdx.x;
  int lane = tid & 63, w = tid >> 6;
  int wr = w >> 1, wc = w & 1;
  long bm0 = (long)bi * TILE_M;
  long bn0 = (long)bj * TILE_N;
  const unsigned short* A = qkv + (long)b * 2048 * 3072;         // q
  const unsigned short* Bm = qkv + (long)b * 2048 * 3072 + 1024; // k
  f32x4 acc[4][4] = {};
  int r = lane & 15, g = lane >> 4;
  for (int kt = 0; kt < 1024 / TILE_K; ++kt) {
    long k0 = (long)kt * TILE_K;
    stage_tile(A + k0, 3072, bm0, lsA, tid);
    stage_tile(Bm + k0, 3072, bn0, lsB, tid);
    __syncthreads();
    bf16x8 aF[4], bF[4];
#pragma unroll
    for (int m = 0; m < 4; ++m)
      aF[m] = *(const bf16x8*)(lsA + (wr * 64 + m * 16 + r) * 32 + g * 8);
#pragma unroll
    for (int n = 0; n < 4; ++n)
      bF[n] = *(const bf16x8*)(lsB + (wc * 64 + n * 16 + r) * 32 + g * 8);
#pragma unroll
    for (int m = 0; m < 4; ++m)
#pragma unroll
      for (int n = 0; n < 4; ++n)
        acc[m][n] = __builtin_amdgcn_mfma_f32_16x16x32_bf16(aF[m], bF[n], acc[m][n], 0, 0, 0);
    __syncthreads();
  }
  unsigned short* S = scores + (long)b * 2048 * 2048;
#pragma unroll
  for (int n = 0; n < 4; ++n) {
    long col = bn0 + wc * 64 + n * 16 + r;
#pragma unroll
    for (int m = 0; m < 4; ++m)
#pragma unroll
      for (int j = 0; j < 4; ++j) {
        long row = bm0 + wr * 64 + m * 16 + g * 4 + j;
        float v = acc[m][n][j] * inv_scale;
        if (col > row) v = 0.0f;  // only possible on diagonal blocks
        S[row * 2048 + col] = f2b(v);
      }
  }
}

// ---------------- GEMM3: y = scores @ v  (f32 out, causal K-loop) ----------------
__global__ __launch_bounds__(256, 2) void gemm3_y(
    const unsigned short* __restrict__ scores,  // [8][2048][2048]
    const unsigned short* __restrict__ vT,      // [8][1024][2048]
    float* __restrict__ out) {                  // [8][2048][1024] f32
  int bn = blockIdx.x, bi = blockIdx.y, b = blockIdx.z;
  __shared__ unsigned short lsA[TILE_M * TILE_K];
  __shared__ unsigned short lsB[TILE_N * TILE_K];
  int tid = threadIdx.x;
  int lane = tid & 63, w = tid >> 6;
  int wr = w >> 1, wc = w & 1;
  long bm0 = (long)bi * TILE_M;
  long bn0 = (long)bn * TILE_N;
  const unsigned short* A = scores + (long)b * 2048 * 2048;
  const unsigned short* Bm = vT + (long)b * 1024 * 2048;
  f32x4 acc[4][4] = {};
  int r = lane & 15, g = lane >> 4;
  int KT = (bi + 1) * (TILE_M / TILE_K);  // only j-tiles at/below the diagonal
  for (int kt = 0; kt < KT; ++kt) {
    long k0 = (long)kt * TILE_K;
    stage_tile(A + k0, 2048, bm0, lsA, tid);
    stage_tile(Bm + k0, 2048, bn0, lsB, tid);
    __syncthreads();
    bf16x8 aF[4], bF[4];
#pragma unroll
    for (int m = 0; m < 4; ++m)
      aF[m] = *(const bf16x8*)(lsA + (wr * 64 + m * 16 + r) * 32 + g * 8);
#pragma unroll
    for (int n = 0; n < 4; ++n)
      bF[n] = *(const bf16x8*)(lsB + (wc * 64 + n * 16 + r) * 32 + g * 8);
#pragma unroll
    for (int m = 0; m < 4; ++m)
#pragma unroll
      for (int n = 0; n < 4; ++n)
        acc[m][n] = __builtin_amdgcn_mfma_f32_16x16x32_bf16(aF[m], bF[n], acc[m][n], 0, 0, 0);
    __syncthreads();
  }
#pragma unroll
  for (int n = 0; n < 4; ++n) {
    long col = bn0 + wc * 64 + n * 16 + r;
#pragma unroll
    for (int m = 0; m < 4; ++m)
#pragma unroll
      for (int j = 0; j < 4; ++j) {
        long row = bm0 + wr * 64 + m * 16 + g * 4 + j;
        out[((long)b * 2048 + row) * 1024 + col] = acc[m][n][j];
      }
  }
}

// ---------------- f32 -> bf16 conversion ----------------
__global__ void cvt_f32_bf16(const float* __restrict__ in,
                             unsigned short* __restrict__ out, long n) {
  long i = ((long)blockIdx.x * blockDim.x + threadIdx.x) * 8;
  if (i + 8 > n) return;
  float4 a = *(const float4*)(in + i);
  float4 b = *(const float4*)(in + i + 4);
  bf16x8 o;
  o[0] = (short)f2b(a.x); o[1] = (short)f2b(a.y);
  o[2] = (short)f2b(a.z); o[3] = (short)f2b(a.w);
  o[4] = (short)f2b(b.x); o[5] = (short)f2b(b.y);
  o[6] = (short)f2b(b.z); o[7] = (short)f2b(b.w);
  *(bf16x8*)(out + i) = o;
}

// ---------------- transpose v: [b][t][d] -> [b][d][t] (bf16) ----------------
__global__ void transpose_v(const unsigned short* __restrict__ qkv,
                            unsigned short* __restrict__ vT) {
  __shared__ unsigned short tile[64][72];
  int t0 = blockIdx.x * 64, d0 = blockIdx.y * 64, b = blockIdx.z;
  int tid = threadIdx.x;
  int sub = tid & 15, grp = tid >> 4;
#pragma unroll
  for (int it = 0; it < 4; ++it) {
    int tt = it * 16 + grp;
    int dd = sub * 4;
    const unsigned short* src =
        qkv + ((long)(b * 2048 + t0 + tt)) * 3072 + 2048 + d0 + dd;
    *(us4*)&tile[tt][dd] = *(const us4*)src;
  }
  __syncthreads();
#pragma unroll
  for (int it = 0; it < 4; ++it) {
    int dd = it * 16 + grp;
    int ts = sub * 4;
    us4 o;
    o[0] = tile[ts + 0][dd];
    o[1] = tile[ts + 1][dd];
    o[2] = tile[ts + 2][dd];
    o[3] = tile[ts + 3][dd];
    *(us4*)(vT + ((long)b * 1024 + d0 + dd) * 2048 + t0 + ts) = o;
  }
}

// ---------------- LayerNorm (in-place on f32 out) ----------------
__global__ void ln_kernel(float* __restrict__ y, const float* __restrict__ wv,
                          const float* __restrict__ bv) {
  __shared__ float sm[4];
  long row = blockIdx.x;
  int tid = threadIdx.x;
  float4 v = *(const float4*)(y + row * 1024 + tid * 4);
  float s = v.x + v.y + v.z + v.w;
#pragma unroll
  for (int o = 32; o > 0; o >>= 1) s += __shfl_xor(s, o, 64);
  if ((tid & 63) == 0) sm[tid >> 6] = s;
  __syncthreads();
  float mu = (sm[0] + sm[1] + sm[2] + sm[3]) * (1.0f / 1024.0f);
  float dx = v.x - mu, dy = v.y - mu, dz = v.z - mu, dw = v.w - mu;
  float sq = dx * dx + dy * dy + dz * dz + dw * dw;
#pragma unroll
  for (int o = 32; o > 0; o >>= 1) sq += __shfl_xor(sq, o, 64);
  __syncthreads();
  if ((tid & 63) == 0) sm[tid >> 6] = sq;
  __syncthreads();
  float var = (sm[0] + sm[1] + sm[2] + sm[3]) * (1.0f / 1024.0f);
  float inv = rsqrtf(var + 1e-5f);
  float4 w4 = *(const float4*)(wv + tid * 4);
  float4 b4 = *(const float4*)(bv + tid * 4);
  float4 o4;
  o4.x = dx * inv * w4.x + b4.x;
  o4.y = dy * inv * w4.y + b4.y;
  o4.z = dz * inv * w4.z + b4.z;
  o4.w = dw * inv * w4.w + b4.w;
  *(float4*)(y + row * 1024 + tid * 4) = o4;
}

extern "C" void kernel_launch(void* const* d_in, const int* in_sizes, int n_in,
                              void* d_out, int out_size, void* d_ws, size_t ws_size,
                              hipStream_t stream) {
  const float* x   = (const float*)d_in[0];   // [8,2048,1024]
  const float* W   = (const float*)d_in[1];   // [3072,1024]
  const float* bq  = (const float*)d_in[2];   // [3072]
  const float* lnw = (const float*)d_in[3];   // [1024]
  const float* lnb = (const float*)d_in[4];   // [1024]
  float* out = (float*)d_out;                 // [8,2048,1024] f32

  char* ws = (char*)d_ws;
  // layout (bytes):
  //   qkv bf16 : [0, 100663296)
  //   vT  bf16 : [100663296, 134217728)
  //   scores   : [134217728, 201326592)   (aliases xb/Wb, freed after gemm1)
  //   xb  bf16 : [134217728, 167772160)
  //   Wb  bf16 : [167772160, 174063616)
  unsigned short* qkv = (unsigned short*)(ws);
  unsigned short* vT  = (unsigned short*)(ws + 100663296L);
  unsigned short* sc  = (unsigned short*)(ws + 134217728L);
  unsigned short* xb  = (unsigned short*)(ws + 134217728L);
  unsigned short* Wb  = (unsigned short*)(ws + 167772160L);

  const float inv_scale = 1.0f / sqrtf(1024.0f * 2048.0f);

  cvt_f32_bf16<<<8192, 256, 0, stream>>>(x, xb, 16384L * 1024);
  cvt_f32_bf16<<<1536, 256, 0, stream>>>(W, Wb, 3072L * 1024);
  gemm1_qkv<<<dim3(24, 128), 256, 0, stream>>>(xb, Wb, bq, qkv);
  transpose_v<<<dim3(32, 16, 8), 256, 0, stream>>>(qkv, vT);
  gemm2_scores<<<dim3(16, 16, 8), 256, 0, stream>>>(qkv, sc, inv_scale);
  gemm3_y<<<dim3(8, 16, 8), 256, 0, stream>>>(sc, vT, out);
  ln_kernel<<<16384, 256, 0, stream>>>(out, lnw, lnb);
}